// Round 1
// baseline (242.940 us; speedup 1.0000x reference)
//
#include <hip/hip_runtime.h>
#include <math.h>

typedef __attribute__((ext_vector_type(8))) short bf16x8;
typedef __attribute__((ext_vector_type(4))) float f32x4;

#define GAT_ALPHA 0.2f

static __device__ __forceinline__ unsigned short f2bf(float x) {
    unsigned u = __float_as_uint(x);
    u += 0x7fffu + ((u >> 16) & 1u);   // RNE; inputs are finite & non-NaN
    return (unsigned short)(u >> 16);
}
static __device__ __forceinline__ float bf2f(unsigned short b) {
    return __uint_as_float(((unsigned)b) << 16);
}

// ---------------- k_prep: h = input @ W (f32), per-row {rowsum, ss=h.c2, sd=h.c1}
// grid N/4, block 512 (y = tid>>7 -> 4 rows, f = tid&127 -> Fout=128 cols)
__global__ __launch_bounds__(512)
void k_prep(const float* __restrict__ input, const float* __restrict__ W,
            const float* __restrict__ c1, const float* __restrict__ c2,
            unsigned short* __restrict__ hb, float* __restrict__ ssx,
            float* __restrict__ sd, int N, int Fin, int Fout)
{
    __shared__ float in_lds[4][256];
    __shared__ float red[4][3];
    const int tid = threadIdx.x;
    const int r0 = blockIdx.x * 4;
    for (int idx = tid; idx < 4 * Fin; idx += 512) {
        int r = idx / Fin, c = idx - r * Fin;
        in_lds[r][c] = input[(size_t)(r0 + r) * Fin + c];
    }
    if (tid < 12) ((float*)red)[tid] = 0.f;
    __syncthreads();
    const int y = tid >> 7, f = tid & 127;
    float acc = 0.f;
    for (int k = 0; k < Fin; ++k)
        acc = fmaf(in_lds[y][k], W[(size_t)k * Fout + f], acc);
    const int row = r0 + y;
    hb[(size_t)row * Fout + f] = f2bf(acc);
    float rs = acc, sv = acc * c2[f], dv = acc * c1[f];
    for (int off = 32; off > 0; off >>= 1) {
        rs += __shfl_xor(rs, off);
        sv += __shfl_xor(sv, off);
        dv += __shfl_xor(dv, off);
    }
    if ((tid & 63) == 0) {
        atomicAdd(&red[y][0], rs);
        atomicAdd(&red[y][1], sv);
        atomicAdd(&red[y][2], dv);
    }
    __syncthreads();
    if (f == 0) {
        float rsum = red[y][0];
        ssx[row] = (rsum != 0.f) ? red[y][1] : -1e30f;  // fold j-mask into score
        sd[row]  = red[y][2];
    }
}

// ---------------- k_smax: global masked max of ssx
__global__ __launch_bounds__(1024)
void k_smax(const float* __restrict__ ssx, float* __restrict__ smax, int N)
{
    __shared__ float red[16];
    const int tid = threadIdx.x;
    float m = -3e38f;
    for (int i = tid; i < N; i += 1024) m = fmaxf(m, ssx[i]);
    for (int off = 32; off > 0; off >>= 1) m = fmaxf(m, __shfl_xor(m, off));
    if ((tid & 63) == 0) red[tid >> 6] = m;
    __syncthreads();
    if (tid == 0) {
        float mm = red[0];
        for (int i = 1; i < 16; ++i) mm = fmaxf(mm, red[i]);
        smax[0] = mm;
    }
}

// ---------------- k_transpose: hb [N][Fout] -> ht [Fout][N]   (bf16 u16 payload)
__global__ __launch_bounds__(256)
void k_transpose(const unsigned short* __restrict__ hb, unsigned short* __restrict__ ht,
                 int N, int Fout)
{
    __shared__ unsigned short t[64][65];
    const int bx = blockIdx.x;   // N/64
    const int by = blockIdx.y;   // Fout/64
    const int tid = threadIdx.x;
    for (int i = 0; i < 16; ++i) {
        int idx = i * 256 + tid; int r = idx >> 6, c = idx & 63;
        t[r][c] = hb[(size_t)(bx * 64 + r) * Fout + by * 64 + c];
    }
    __syncthreads();
    for (int i = 0; i < 16; ++i) {
        int idx = i * 256 + tid; int r = idx >> 6, c = idx & 63;
        ht[(size_t)(by * 64 + r) * N + bx * 64 + c] = t[c][r];
    }
}

// ---------------- k_attn: flash-style masked softmax + P@h via MFMA
// grid M/16 blocks, 256 threads (4 waves). BM=16 rows, JT=128, Fout=128.
// wave w owns output cols [32w, 32w+32) as two 16x16 MFMA tiles.
__global__ __launch_bounds__(256)
void k_attn(const int* __restrict__ adj, const unsigned short* __restrict__ ht,
            const float* __restrict__ ssx, const float* __restrict__ sd,
            const float* __restrict__ smaxp, float* __restrict__ out,
            int N, int M, int Fout)
{
    __shared__ alignas(16) char plds[16 * 128 * 2];   // swizzled bf16 P tile
    __shared__ float sdm[16], mrow[16], dlds[16];
    const int tid = threadIdx.x;
    const int rb = blockIdx.x * 16;

    if (tid < 16) {
        int rr = rb + tid; if (rr > M - 1) rr = M - 1;
        float s = sd[rr];
        float v = s + smaxp[0];
        sdm[tid]  = s;
        mrow[tid] = fmaxf(v, GAT_ALPHA * v);   // leakyrelu (monotone) of the max bound
        dlds[tid] = 0.f;
    }
    __syncthreads();

    const int cgrp = tid >> 5;             // 0..7
    const int c4   = (tid & 31) << 2;      // col*4 within j-tile
    const int r0 = cgrp, r1 = cgrp + 8;
    const size_t arow0 = (size_t)min(rb + r0, M - 1) * N;
    const size_t arow1 = (size_t)min(rb + r1, M - 1) * N;
    const float s0 = sdm[r0], m0 = mrow[r0];
    const float s1 = sdm[r1], m1 = mrow[r1];

    const int wl = tid & 63;
    const int w  = tid >> 6;               // wave id -> col group
    const int am = wl & 15;                // A-frag row / B-frag col / D col
    const int kg = wl >> 4;                // k-group 0..3
    const int abase = am * 256;            // P row stride = 128*2 bytes
    const int aswz  = (am & 7) << 4;       // bank-conflict XOR swizzle (G4)
    const unsigned short* bp0 = ht + (size_t)(32 * w + am) * N + 8 * kg;
    const unsigned short* bp1 = bp0 + (size_t)16 * N;

    const int NT = N >> 7;
    int4 a0 = *(const int4*)(adj + arow0 + c4);
    int4 a1 = *(const int4*)(adj + arow1 + c4);
    float4 sv = *(const float4*)(ssx + c4);
    float dp0 = 0.f, dp1 = 0.f;
    f32x4 acc0 = {0.f, 0.f, 0.f, 0.f}, acc1 = {0.f, 0.f, 0.f, 0.f};

    for (int jt = 0; jt < NT; ++jt) {
        int4 n0 = a0, n1 = a1; float4 nv = sv;
        if (jt + 1 < NT) {                         // 1-deep prefetch of next adj tile
            const size_t joff = (size_t)(jt + 1) * 128 + c4;
            n0 = *(const int4*)(adj + arow0 + joff);
            n1 = *(const int4*)(adj + arow1 + joff);
            nv = *(const float4*)(ssx + joff);
        }
        ushort4 pw0, pw1;
        {
            const int*   ai = (const int*)&a0;
            const float* sf = (const float*)&sv;
            unsigned short* pu = (unsigned short*)&pw0;
            float d = 0.f;
            #pragma unroll
            for (int i = 0; i < 4; ++i) {
                float v = s0 + sf[i];
                float e = fminf(fmaxf(v, GAT_ALPHA * v) - m0, 0.f);
                float p = (ai[i] > 0) ? __expf(e) : 0.f;
                unsigned short pb = f2bf(p);
                pu[i] = pb;
                d += bf2f(pb);                      // denom over the same rounded values
            }
            dp0 += d;
        }
        {
            const int*   ai = (const int*)&a1;
            const float* sf = (const float*)&sv;
            unsigned short* pu = (unsigned short*)&pw1;
            float d = 0.f;
            #pragma unroll
            for (int i = 0; i < 4; ++i) {
                float v = s1 + sf[i];
                float e = fminf(fmaxf(v, GAT_ALPHA * v) - m1, 0.f);
                float p = (ai[i] > 0) ? __expf(e) : 0.f;
                unsigned short pb = f2bf(p);
                pu[i] = pb;
                d += bf2f(pb);
            }
            dp1 += d;
        }
        *(ushort4*)(plds + r0 * 256 + ((c4 << 1) ^ ((r0 & 7) << 4))) = pw0;
        *(ushort4*)(plds + r1 * 256 + ((c4 << 1) ^ ((r1 & 7) << 4))) = pw1;
        __syncthreads();

        const unsigned short* bj0 = bp0 + (size_t)jt * 128;
        const unsigned short* bj1 = bp1 + (size_t)jt * 128;
        #pragma unroll
        for (int kb = 0; kb < 4; ++kb) {
            bf16x8 af = *(const bf16x8*)(plds + abase + ((kb * 64 + 16 * kg) ^ aswz));
            bf16x8 b0 = *(const bf16x8*)(bj0 + kb * 32);
            bf16x8 b1 = *(const bf16x8*)(bj1 + kb * 32);
            acc0 = __builtin_amdgcn_mfma_f32_16x16x32_bf16(af, b0, acc0, 0, 0, 0);
            acc1 = __builtin_amdgcn_mfma_f32_16x16x32_bf16(af, b1, acc1, 0, 0, 0);
        }
        __syncthreads();
        a0 = n0; a1 = n1; sv = nv;
    }

    atomicAdd(&dlds[r0], dp0);
    atomicAdd(&dlds[r1], dp1);
    __syncthreads();

    // epilogue: D layout col=lane&15, row=(lane>>4)*4+reg   [measured m89]
    const int ocol = 32 * w + am;
    #pragma unroll
    for (int reg = 0; reg < 4; ++reg) {
        const int r = kg * 4 + reg;
        const int grow = rb + r;
        if (grow < M) {
            float dsum = dlds[r];
            float inv = (dsum > 0.f) ? 1.f / dsum : 0.f;
            float v0 = acc0[reg] * inv;
            float v1 = acc1[reg] * inv;
            v0 = (v0 > 0.f) ? v0 : expm1f(v0);     // ELU (alpha=1)
            v1 = (v1 > 0.f) ? v1 : expm1f(v1);
            out[(size_t)grow * Fout + ocol]      = v0;
            out[(size_t)grow * Fout + ocol + 16] = v1;
        }
    }
}

extern "C" void kernel_launch(void* const* d_in, const int* in_sizes, int n_in,
                              void* d_out, int out_size, void* d_ws, size_t ws_size,
                              hipStream_t stream)
{
    const float* input = (const float*)d_in[0];
    const float* W     = (const float*)d_in[1];
    const float* c1    = (const float*)d_in[2];
    const float* c2    = (const float*)d_in[3];
    const int*   adj   = (const int*)d_in[4];

    const int Fout = in_sizes[2];          // c1: [Fout,1]
    const int Fin  = in_sizes[1] / Fout;   // W: [Fin,Fout]
    const int N    = in_sizes[0] / Fin;    // input: [N,Fin]
    const int M    = out_size / Fout;
    float* out = (float*)d_out;

    char* ws = (char*)d_ws;
    unsigned short* hb = (unsigned short*)ws;                              // N*Fout bf16
    unsigned short* ht = (unsigned short*)(ws + (size_t)N * Fout * 2);     // Fout*N bf16
    float* ssx  = (float*)(ws + (size_t)N * Fout * 4);
    float* sd   = ssx + N;
    float* smax = sd + N;

    k_prep<<<N / 4, 512, 0, stream>>>(input, W, c1, c2, hb, ssx, sd, N, Fin, Fout);
    k_smax<<<1, 1024, 0, stream>>>(ssx, smax, N);
    k_transpose<<<dim3(N / 64, Fout / 64), 256, 0, stream>>>(hb, ht, N, Fout);
    k_attn<<<(M + 15) / 16, 256, 0, stream>>>(adj, ht, ssx, sd, smax, out, N, M, Fout);
}

// Round 2
// 239.832 us; speedup vs baseline: 1.0130x; 1.0130x over previous
//
#include <hip/hip_runtime.h>
#include <math.h>

typedef __attribute__((ext_vector_type(8))) short bf16x8;
typedef __attribute__((ext_vector_type(4))) float f32x4;

#define GAT_ALPHA 0.2f
#define NSPLIT 8

static __device__ __forceinline__ unsigned short f2bf(float x) {
    unsigned u = __float_as_uint(x);
    u += 0x7fffu + ((u >> 16) & 1u);   // RNE; inputs are finite & non-NaN
    return (unsigned short)(u >> 16);
}
static __device__ __forceinline__ float bf2f(unsigned short b) {
    return __uint_as_float(((unsigned)b) << 16);
}

// ---------------- k_prep: h = input @ W (f32), per-row {rowsum, ss=h.c2, sd=h.c1}
__global__ __launch_bounds__(512)
void k_prep(const float* __restrict__ input, const float* __restrict__ W,
            const float* __restrict__ c1, const float* __restrict__ c2,
            unsigned short* __restrict__ hb, float* __restrict__ ssx,
            float* __restrict__ sd, int N, int Fin, int Fout)
{
    __shared__ float in_lds[4][256];
    __shared__ float red[4][3];
    const int tid = threadIdx.x;
    const int r0 = blockIdx.x * 4;
    for (int idx = tid; idx < 4 * Fin; idx += 512) {
        int r = idx / Fin, c = idx - r * Fin;
        in_lds[r][c] = input[(size_t)(r0 + r) * Fin + c];
    }
    if (tid < 12) ((float*)red)[tid] = 0.f;
    __syncthreads();
    const int y = tid >> 7, f = tid & 127;
    float acc = 0.f;
    for (int k = 0; k < Fin; ++k)
        acc = fmaf(in_lds[y][k], W[(size_t)k * Fout + f], acc);
    const int row = r0 + y;
    hb[(size_t)row * Fout + f] = f2bf(acc);
    float rs = acc, sv = acc * c2[f], dv = acc * c1[f];
    for (int off = 32; off > 0; off >>= 1) {
        rs += __shfl_xor(rs, off);
        sv += __shfl_xor(sv, off);
        dv += __shfl_xor(dv, off);
    }
    if ((tid & 63) == 0) {
        atomicAdd(&red[y][0], rs);
        atomicAdd(&red[y][1], sv);
        atomicAdd(&red[y][2], dv);
    }
    __syncthreads();
    if (f == 0) {
        float rsum = red[y][0];
        ssx[row] = (rsum != 0.f) ? red[y][1] : -1e30f;  // fold j-mask into score
        sd[row]  = red[y][2];
    }
}

// ---------------- k_smax: global masked max of ssx
__global__ __launch_bounds__(1024)
void k_smax(const float* __restrict__ ssx, float* __restrict__ smax, int N)
{
    __shared__ float red[16];
    const int tid = threadIdx.x;
    float m = -3e38f;
    for (int i = tid; i < N; i += 1024) m = fmaxf(m, ssx[i]);
    for (int off = 32; off > 0; off >>= 1) m = fmaxf(m, __shfl_xor(m, off));
    if ((tid & 63) == 0) red[tid >> 6] = m;
    __syncthreads();
    if (tid == 0) {
        float mm = red[0];
        for (int i = 1; i < 16; ++i) mm = fmaxf(mm, red[i]);
        smax[0] = mm;
    }
}

// ---------------- k_transpose: hb [N][Fout] -> ht [Fout][N]
__global__ __launch_bounds__(256)
void k_transpose(const unsigned short* __restrict__ hb, unsigned short* __restrict__ ht,
                 int N, int Fout)
{
    __shared__ unsigned short t[64][65];
    const int bx = blockIdx.x;   // N/64
    const int by = blockIdx.y;   // Fout/64
    const int tid = threadIdx.x;
    for (int i = 0; i < 16; ++i) {
        int idx = i * 256 + tid; int r = idx >> 6, c = idx & 63;
        t[r][c] = hb[(size_t)(bx * 64 + r) * Fout + by * 64 + c];
    }
    __syncthreads();
    for (int i = 0; i < 16; ++i) {
        int idx = i * 256 + tid; int r = idx >> 6, c = idx & 63;
        ht[(size_t)(by * 64 + r) * N + bx * 64 + c] = t[c][r];
    }
}

// ---------------- k_attn: wave-independent flash attention over a j-chunk.
// grid (M/16, NSPLIT), block 64 (1 wave). Each wave: 16 rows x 128 out cols,
// j in [split*chunk, (split+1)*chunk). P built directly in A-frag layout:
// lane l holds P[row = l&15][k = 8*(l>>4)+e], e=0..7. No LDS, no barriers.
__global__ __launch_bounds__(64)
void k_attn(const int* __restrict__ adj, const unsigned short* __restrict__ ht,
            const float* __restrict__ ssx, const float* __restrict__ sd,
            const float* __restrict__ smaxp, float* __restrict__ outacc,
            float* __restrict__ denom, int N, int M, int Fout)
{
    const int wl = threadIdx.x;
    const int am = wl & 15;            // row within 16-row strip
    const int kg = wl >> 4;            // k-group 0..3
    const int rb = blockIdx.x * 16;
    const int chunk = N / NSPLIT;
    const int j0 = blockIdx.y * chunk;

    const int row = rb + am;           // M % 16 == 0
    const float s = sd[row];
    float vb = s + smaxp[0];
    const float m = fmaxf(vb, GAT_ALPHA * vb);   // upper bound of valid scores

    const size_t abase = (size_t)row * N + j0 + 8 * kg;
    const unsigned short* hbase = ht + j0 + 8 * kg;

    f32x4 acc[8];
    #pragma unroll
    for (int c = 0; c < 8; ++c) acc[c] = (f32x4){0.f, 0.f, 0.f, 0.f};
    float dloc = 0.f;

    const int NT = chunk >> 5;         // j-steps of 32
    int4 a0 = *(const int4*)(adj + abase);
    int4 a1 = *(const int4*)(adj + abase + 4);
    float4 s0 = *(const float4*)(ssx + j0 + 8 * kg);
    float4 s1 = *(const float4*)(ssx + j0 + 8 * kg + 4);

    for (int jt = 0; jt < NT; ++jt) {
        int4 na0 = a0, na1 = a1; float4 ns0 = s0, ns1 = s1;
        if (jt + 1 < NT) {
            const size_t off = abase + (size_t)(jt + 1) * 32;
            na0 = *(const int4*)(adj + off);
            na1 = *(const int4*)(adj + off + 4);
            ns0 = *(const float4*)(ssx + j0 + 8 * kg + (jt + 1) * 32);
            ns1 = *(const float4*)(ssx + j0 + 8 * kg + (jt + 1) * 32 + 4);
        }
        // build A fragment (8 P values) in registers
        bf16x8 af;
        {
            const int*   ai0 = (const int*)&a0;
            const int*   ai1 = (const int*)&a1;
            const float* sf0 = (const float*)&s0;
            const float* sf1 = (const float*)&s1;
            unsigned short* pu = (unsigned short*)&af;
            float d = 0.f;
            #pragma unroll
            for (int i = 0; i < 4; ++i) {
                float v = s + sf0[i];
                float e = fminf(fmaxf(v, GAT_ALPHA * v) - m, 0.f);
                float p = (ai0[i] > 0) ? __expf(e) : 0.f;
                unsigned short pb = f2bf(p);
                pu[i] = pb;
                d += bf2f(pb);
            }
            #pragma unroll
            for (int i = 0; i < 4; ++i) {
                float v = s + sf1[i];
                float e = fminf(fmaxf(v, GAT_ALPHA * v) - m, 0.f);
                float p = (ai1[i] > 0) ? __expf(e) : 0.f;
                unsigned short pb = f2bf(p);
                pu[4 + i] = pb;
                d += bf2f(pb);
            }
            dloc += d;
        }
        const unsigned short* hj = hbase + (size_t)jt * 32;
        #pragma unroll
        for (int c = 0; c < 8; ++c) {
            bf16x8 bf = *(const bf16x8*)(hj + (size_t)(16 * c + am) * N);
            acc[c] = __builtin_amdgcn_mfma_f32_16x16x32_bf16(af, bf, acc[c], 0, 0, 0);
        }
        a0 = na0; a1 = na1; s0 = ns0; s1 = ns1;
    }

    // denominator: sum over k-groups for each row
    dloc += __shfl_xor(dloc, 16);
    dloc += __shfl_xor(dloc, 32);
    if (kg == 0) atomicAdd(&denom[row], dloc);

    // D layout: col = lane&15, row = (lane>>4)*4 + reg   [measured m89]
    #pragma unroll
    for (int c = 0; c < 8; ++c) {
        #pragma unroll
        for (int reg = 0; reg < 4; ++reg) {
            const int r = rb + kg * 4 + reg;
            atomicAdd(&outacc[(size_t)r * Fout + 16 * c + am], acc[c][reg]);
        }
    }
}

// ---------------- k_norm: out = elu(out / denom[row]) in place
__global__ __launch_bounds__(256)
void k_norm(float* __restrict__ out, const float* __restrict__ denom, int Fout4)
{
    const int idx = blockIdx.x * 256 + threadIdx.x;   // float4 index
    const int row = idx / Fout4;
    float d = denom[row];
    float inv = (d > 0.f) ? 1.f / d : 0.f;
    float4 v = ((const float4*)out)[idx];
    float* vp = (float*)&v;
    #pragma unroll
    for (int i = 0; i < 4; ++i) {
        float x = vp[i] * inv;
        vp[i] = (x > 0.f) ? x : expm1f(x);
    }
    ((float4*)out)[idx] = v;
}

extern "C" void kernel_launch(void* const* d_in, const int* in_sizes, int n_in,
                              void* d_out, int out_size, void* d_ws, size_t ws_size,
                              hipStream_t stream)
{
    const float* input = (const float*)d_in[0];
    const float* W     = (const float*)d_in[1];
    const float* c1    = (const float*)d_in[2];
    const float* c2    = (const float*)d_in[3];
    const int*   adj   = (const int*)d_in[4];

    const int Fout = in_sizes[2];          // c1: [Fout,1]
    const int Fin  = in_sizes[1] / Fout;   // W: [Fin,Fout]
    const int N    = in_sizes[0] / Fin;    // input: [N,Fin]
    const int M    = out_size / Fout;
    float* out = (float*)d_out;

    char* ws = (char*)d_ws;
    unsigned short* hb = (unsigned short*)ws;                              // N*Fout bf16
    unsigned short* ht = (unsigned short*)(ws + (size_t)N * Fout * 2);     // Fout*N bf16
    float* ssx   = (float*)(ws + (size_t)N * Fout * 4);
    float* sd    = ssx + N;
    float* smax  = sd + N;
    float* denom = smax + 1;                                               // M floats

    hipMemsetAsync(out, 0, (size_t)M * Fout * sizeof(float), stream);
    hipMemsetAsync(denom, 0, (size_t)M * sizeof(float), stream);

    k_prep<<<N / 4, 512, 0, stream>>>(input, W, c1, c2, hb, ssx, sd, N, Fin, Fout);
    k_smax<<<1, 1024, 0, stream>>>(ssx, smax, N);
    k_transpose<<<dim3(N / 64, Fout / 64), 256, 0, stream>>>(hb, ht, N, Fout);
    k_attn<<<dim3(M / 16, NSPLIT), 64, 0, stream>>>(adj, ht, ssx, sd, smax, out, denom, N, M, Fout);
    k_norm<<<(M * Fout / 4 + 255) / 256, 256, 0, stream>>>(out, denom, Fout / 4);
}